// Round 6
// baseline (10145.525 us; speedup 1.0000x reference)
//
#include <hip/hip_runtime.h>
#include <hip/hip_bf16.h>

typedef __attribute__((ext_vector_type(8))) short  bf16x8;
typedef __attribute__((ext_vector_type(4))) float  f32x4;
typedef __attribute__((ext_vector_type(4))) unsigned int u32x4;

#define EOS 2
#define S 1024
#define B 64
#define E 256
#define H 512
#define NROLE 128
// region: flags 128 x uint stride 16B (2048) | test 128 x uint (512) | pad to 4096
//         | hbuf 2 bufs x {hi,lo} x [64][512] bf16 (524288)
#define REGION (4096 + 2 * 2 * B * H * 2)   // 528384
#define GETREG_XCC 6164    // HW_REG_XCC_ID: id=20, offset=0, size=4
#define MAGIC 0x5AC30000u

#define AT_LD(p)    __hip_atomic_load((p), __ATOMIC_RELAXED, __HIP_MEMORY_SCOPE_AGENT)
#define AT_ST(p, v) __hip_atomic_store((p), (v), __ATOMIC_RELAXED, __HIP_MEMORY_SCOPE_AGENT)
#define AT_ADD(p,v) __hip_atomic_fetch_add((p), (v), __ATOMIC_RELAXED, __HIP_MEMORY_SCOPE_AGENT)

__device__ __forceinline__ unsigned short f2bf(float f) {
    unsigned int u = __builtin_bit_cast(unsigned int, f);
    unsigned int r = (u + 0x7FFFu + ((u >> 16) & 1u)) >> 16;
    return (unsigned short)r;
}
__device__ __forceinline__ float bf2f(unsigned short s) {
    unsigned int u = ((unsigned int)s) << 16;
    return __builtin_bit_cast(float, u);
}
__device__ __forceinline__ unsigned int pk2(float x, float y) {
    unsigned int ux = __builtin_bit_cast(unsigned int, x) + 0x8000u;
    unsigned int uy = __builtin_bit_cast(unsigned int, y) + 0x8000u;
    return (ux >> 16) | (uy & 0xFFFF0000u);
}
__device__ __forceinline__ bf16x8 pack8hu(float4 a, float4 b) {
    union { unsigned int d[4]; bf16x8 v; } u;
    u.d[0] = pk2(a.x, a.y); u.d[1] = pk2(a.z, a.w);
    u.d[2] = pk2(b.x, b.y); u.d[3] = pk2(b.z, b.w);
    return u.v;
}
__device__ __forceinline__ bf16x8 pack8rne(float4 a, float4 b) {
    union { unsigned short s[8]; bf16x8 v; } u;
    u.s[0] = f2bf(a.x); u.s[1] = f2bf(a.y); u.s[2] = f2bf(a.z); u.s[3] = f2bf(a.w);
    u.s[4] = f2bf(b.x); u.s[5] = f2bf(b.y); u.s[6] = f2bf(b.z); u.s[7] = f2bf(b.w);
    return u.v;
}

// ---------------------------------------------------------------------------
// dest[t][b] = k-th EOS index (0..31) or -1
// ---------------------------------------------------------------------------
__global__ __launch_bounds__(256) void dest_kernel(const int* __restrict__ tokens,
                                                   int* __restrict__ dest) {
    const int b = blockIdx.x, tid = threadIdx.x;
    const int l = tid & 63, w = tid >> 6;
    const int base = tid * 4;
    int m[4], cnt = 0;
#pragma unroll
    for (int i = 0; i < 4; ++i) {
        int tok = tokens[b * S + base + i];
        m[i] = (tok == EOS) ? 1 : 0;
        cnt += m[i];
    }
    int inc = cnt;
#pragma unroll
    for (int d = 1; d < 64; d <<= 1) {
        int v = __shfl_up(inc, d, 64);
        if (l >= d) inc += v;
    }
    __shared__ int wt[4];
    if (l == 63) wt[w] = inc;
    __syncthreads();
    int off = 0;
    for (int k = 0; k < 4; ++k)
        if (k < w) off += wt[k];
    int run = off + inc - cnt;
#pragma unroll
    for (int i = 0; i < 4; ++i) {
        dest[(base + i) * B + b] = m[i] ? run : -1;
        run += m[i];
    }
}

// ---------------------------------------------------------------------------
// Persistent fused GRU with verified XCD-local fast path + agent-scope
// fallback. 1024 blocks x 64 thr (one wave each).
// Counters page (device-scope atomics): ctr[0..7] xcd claim; ctr[16+x] vrdy;
// ctr[32+x] vdone; ctr[48+x] verdict; ctr[64] fctr; ctr[65] fdecision;
// ctr[66] success.
// ---------------------------------------------------------------------------
__global__ __launch_bounds__(64, 1) void gru_kernel(
    const int* __restrict__ tokens, const float* __restrict__ emb,
    const float* __restrict__ w_ih, const float* __restrict__ w_hh,
    const float* __restrict__ b_ih, const float* __restrict__ b_hh,
    const int* __restrict__ dest,
    char* ws, int nreg, float* __restrict__ out) {

    const int l = threadIdx.x;
    unsigned int* ctr = (unsigned int*)ws;
    const unsigned int xcc = __builtin_amdgcn_s_getreg(GETREG_XCC) & 7u;

    bool fast = false;
    int role = -1;
    char* region = nullptr;

    // ---- try to join this XCD's cohort and VERIFY the L2-local protocol ----
    if ((int)xcc < nreg) {
        unsigned int r = 0;
        if (l == 0) r = AT_ADD(&ctr[xcc], 1u);
        r = (unsigned int)__shfl((int)r, 0);
        if (r < NROLE) {
            region = ws + 1024 + (size_t)xcc * REGION;
            unsigned int* test = (unsigned int*)(region + 2048);
            // prime L1 with the old (zero) value of the slot we'll verify
            {
                const unsigned int* pp = &test[(r + 1 + (unsigned)l) & 127];
                unsigned int pv;
                asm volatile("global_load_dword %0, %1, off\n\ts_waitcnt vmcnt(0)"
                             : "=&v"(pv) : "v"(pp) : "memory");
                (void)pv;
            }
            // publish magic (plain store -> write-through to this XCD's L2)
            if (l == 0) test[r] = MAGIC ^ r;
            asm volatile("s_waitcnt vmcnt(0)" ::: "memory");
            // rendezvous 1 (device-scope, trustworthy)
            int ok = 1;
            if (l == 0) AT_ADD(&ctr[16 + xcc], 1u);
            {
                int g = 1 << 12; unsigned int c = 0;
                for (;;) {
                    if (l == 0) c = AT_LD(&ctr[16 + xcc]);
                    c = (unsigned int)__shfl((int)c, 0);
                    if (c >= NROLE) break;
                    if (--g <= 0) { ok = 0; break; }
                    __builtin_amdgcn_s_sleep(4);
                }
            }
            if (ok) {
                // the protocol under test: buffer_inv (L1-only) + plain load
                asm volatile("buffer_inv" ::: "memory");
                const unsigned int idx = (r + 1 + (unsigned)l) & 127;
                unsigned int got;
                asm volatile("global_load_dword %0, %1, off\n\ts_waitcnt vmcnt(0)"
                             : "=&v"(got) : "v"(&test[idx]) : "memory");
                if (!__all((int)(got == (MAGIC ^ idx)))) ok = 0;
            }
            if (!ok && l == 0) AT_ADD(&ctr[48 + xcc], 1u);   // poison verdict
            if (l == 0) AT_ADD(&ctr[32 + xcc], 1u);          // vdone
            {
                int g = 1 << 12; unsigned int c = 0;
                for (;;) {
                    if (l == 0) c = AT_LD(&ctr[32 + xcc]);
                    c = (unsigned int)__shfl((int)c, 0);
                    if (c >= NROLE) break;
                    if (--g <= 0) break;
                    __builtin_amdgcn_s_sleep(4);
                }
            }
            unsigned int v = 1;
            if (l == 0) v = AT_LD(&ctr[48 + xcc]);
            v = (unsigned int)__shfl((int)v, 0);
            if (ok && v == 0) {
                fast = true; role = (int)r;
                if (l == 0) AT_ST(&ctr[66], 1u);   // success signal
            }
        }
    }

    // ---- fallback enrollment (agent-scope protocol, round-3-verified) ----
    if (!fast) {
        unsigned int f = 0;
        if (l == 0) f = AT_ADD(&ctr[64], 1u);
        f = (unsigned int)__shfl((int)f, 0);
        if (f >= NROLE) return;
        if (f == 0) {   // leader decides run(1)/abort(2), single source of truth
            unsigned int d = 1;
            int g = 1 << 14;
            for (;;) {
                unsigned int s = 0, c = 0;
                if (l == 0) { s = AT_LD(&ctr[66]); c = AT_LD(&ctr[64]); }
                s = (unsigned int)__shfl((int)s, 0);
                c = (unsigned int)__shfl((int)c, 0);
                if (s) { d = 2; break; }
                if (c >= NROLE) { d = 1; break; }
                if (--g <= 0) { d = 1; break; }
                __builtin_amdgcn_s_sleep(8);
            }
            if (l == 0) AT_ST(&ctr[65], d);
            if (d == 2) return;
        } else {
            unsigned int d = 0;
            int g = 1 << 15;
            for (;;) {
                if (l == 0) d = AT_LD(&ctr[65]);
                d = (unsigned int)__shfl((int)d, 0);
                if (d) break;
                if (--g <= 0) { d = 1; break; }
                __builtin_amdgcn_s_sleep(8);
            }
            if (d == 2) return;
        }
        role = (int)f;
        region = ws + 1024 + (size_t)nreg * REGION;   // dedicated fallback region
    }

    // ------------------- common setup -------------------
    const int j = role & 31;             // unit group
    const int w = role >> 5;             // batch slice
    const int l15 = l & 15, quad = l >> 4;
    const int unit = j * 16 + l15;
    const int koff = quad * 8;
    const int brow = w * 16 + l15;
    unsigned int* flagsw = (unsigned int*)region;
    unsigned short* hbuf = (unsigned short*)(region + 4096);

    bf16x8 Wh[3][16];
#pragma unroll
    for (int g = 0; g < 3; ++g)
#pragma unroll
        for (int kt = 0; kt < 16; ++kt) {
            const float* p = &w_hh[(size_t)(g * H + unit) * H + kt * 32 + koff];
            Wh[g][kt] = pack8rne(*(const float4*)p, *(const float4*)(p + 4));
        }
    bf16x8 Wi[3][8];
#pragma unroll
    for (int g = 0; g < 3; ++g)
#pragma unroll
        for (int kt = 0; kt < 8; ++kt) {
            const float* p = &w_ih[(size_t)(g * H + unit) * E + kt * 32 + koff];
            Wi[g][kt] = pack8rne(*(const float4*)p, *(const float4*)(p + 4));
        }
    const float bi0 = b_ih[unit], bi1 = b_ih[H + unit], bi2 = b_ih[2 * H + unit];
    const float bh0 = b_hh[unit], bh1 = b_hh[H + unit], bh2 = b_hh[2 * H + unit];

    float hown[4] = {0.f, 0.f, 0.f, 0.f};
    int tok_next = tokens[brow * S];

    for (int t = 0; t < S; ++t) {
        // --- independent work first (hides under producer wait) ---
        const int tok = tok_next;
        const float* er = &emb[(size_t)tok * E + koff];
        float4 ef[8][2];
#pragma unroll
        for (int kt = 0; kt < 8; ++kt) {
            ef[kt][0] = *(const float4*)(er + kt * 32);
            ef[kt][1] = *(const float4*)(er + kt * 32 + 4);
        }
        if (t + 1 < S) tok_next = tokens[brow * S + t + 1];
        int4 dst4 = *(const int4*)&dest[t * B + w * 16 + quad * 4];

        f32x4 gi0 = {bi0, bi0, bi0, bi0};
        f32x4 gi1 = {bi1, bi1, bi1, bi1};
        f32x4 gi2 = {bi2, bi2, bi2, bi2};
#pragma unroll
        for (int kt = 0; kt < 8; ++kt) {
            bf16x8 af = pack8hu(ef[kt][0], ef[kt][1]);
            gi0 = __builtin_amdgcn_mfma_f32_16x16x32_bf16(af, Wi[0][kt], gi0, 0, 0, 0);
            gi1 = __builtin_amdgcn_mfma_f32_16x16x32_bf16(af, Wi[1][kt], gi1, 0, 0, 0);
            gi2 = __builtin_amdgcn_mfma_f32_16x16x32_bf16(af, Wi[2][kt], gi2, 0, 0, 0);
        }

        // --- wait for h[t]: the 32 producers of slice w in this region ---
        const unsigned int fidx = (unsigned int)((w * 32 + (l & 31)) * 4);
        if (fast) {
            int pb = 1 << 20;
            for (;;) {
                asm volatile("buffer_inv" ::: "memory");   // L1-only invalidate
                unsigned int f = flagsw[fidx];             // plain load -> L2
                if (__all((int)(f >= (unsigned int)t))) break;
                if (--pb <= 0) break;
            }
        } else {
            int pb = 1 << 20;
            while (pb > 0) {
                unsigned int f = AT_LD(&flagsw[fidx]);
                if (__all((int)(f >= (unsigned int)t))) break;
                --pb;
            }
        }

        // --- gh = b_hh + h . W_hh^T (bf16 hi+lo split) ---
        const unsigned short* hs = hbuf + (size_t)(t & 1) * (2 * B * H);
        f32x4 a0 = {bh0, bh0, bh0, bh0};
        f32x4 a1 = {bh1, bh1, bh1, bh1};
        f32x4 a2 = {bh2, bh2, bh2, bh2};
#pragma unroll
        for (int half = 0; half < 2; ++half) {
            const unsigned short* ph = hs + brow * H + half * 256 + koff;
            const unsigned short* pl = ph + B * H;
            u32x4 rh[8], rl[8];
            if (fast) {
#pragma unroll
                for (int k = 0; k < 8; ++k) {   // plain loads; L1 cleared by
                    rh[k] = *(const u32x4*)(ph + k * 32);   // the poll's inv
                    rl[k] = *(const u32x4*)(pl + k * 32);
                }
            } else {
#pragma unroll
                for (int k = 0; k < 8; ++k) {
                    union { unsigned long long q[2]; u32x4 v; } th, tl;
                    const unsigned long long* qh = (const unsigned long long*)(ph + k * 32);
                    const unsigned long long* ql = (const unsigned long long*)(pl + k * 32);
                    th.q[0] = AT_LD(qh); th.q[1] = AT_LD(qh + 1);
                    tl.q[0] = AT_LD(ql); tl.q[1] = AT_LD(ql + 1);
                    rh[k] = th.v; rl[k] = tl.v;
                }
            }
#pragma unroll
            for (int k = 0; k < 8; ++k) {
                const int kt = half * 8 + k;
                bf16x8 ah = __builtin_bit_cast(bf16x8, rh[k]);
                bf16x8 al = __builtin_bit_cast(bf16x8, rl[k]);
                a0 = __builtin_amdgcn_mfma_f32_16x16x32_bf16(ah, Wh[0][kt], a0, 0, 0, 0);
                a1 = __builtin_amdgcn_mfma_f32_16x16x32_bf16(ah, Wh[1][kt], a1, 0, 0, 0);
                a2 = __builtin_amdgcn_mfma_f32_16x16x32_bf16(ah, Wh[2][kt], a2, 0, 0, 0);
                a0 = __builtin_amdgcn_mfma_f32_16x16x32_bf16(al, Wh[0][kt], a0, 0, 0, 0);
                a1 = __builtin_amdgcn_mfma_f32_16x16x32_bf16(al, Wh[1][kt], a1, 0, 0, 0);
                a2 = __builtin_amdgcn_mfma_f32_16x16x32_bf16(al, Wh[2][kt], a2, 0, 0, 0);
            }
        }

        // --- gates + h[t+1] stores ---
        unsigned short* hd = hbuf + (size_t)((t + 1) & 1) * (2 * B * H);
        unsigned int* hd_hi32 = (unsigned int*)hd;
        unsigned int* hd_lo32 = (unsigned int*)(hd + B * H);
        const bool even = (l15 & 1) == 0;
        int dsts[4] = {dst4.x, dst4.y, dst4.z, dst4.w};
#pragma unroll
        for (int r = 0; r < 4; ++r) {
            const int b = w * 16 + quad * 4 + r;
            float rg = 1.f / (1.f + __expf(-(gi0[r] + a0[r])));
            float zg = 1.f / (1.f + __expf(-(gi1[r] + a1[r])));
            float x = gi2[r] + rg * a2[r];
            x = fminf(15.f, fmaxf(-15.f, x));
            float e = __expf(-2.f * x);
            float ng = (1.f - e) / (1.f + e);
            float h = (1.f - zg) * ng + zg * hown[r];   // fp32 carry (exact)
            hown[r] = h;
            unsigned short hi16 = f2bf(h);
            unsigned short lo16 = f2bf(h - bf2f(hi16));
            if (fast) {
                hd[(size_t)b * H + unit] = hi16;             // plain -> L2
                hd[(size_t)(B * H) + b * H + unit] = lo16;
            } else {
                unsigned int pk = ((unsigned int)lo16 << 16) | (unsigned int)hi16;
                unsigned int sw = (unsigned int)__shfl_xor((int)pk, 1);
                unsigned int val = even ? ((pk & 0xFFFFu) | (sw << 16))
                                        : ((sw >> 16) | (pk & 0xFFFF0000u));
                unsigned int didx = ((unsigned int)(b * H + unit)) >> 1;
                AT_ST((even ? hd_hi32 : hd_lo32) + didx, val);
            }
            if (dsts[r] >= 0)
                out[((size_t)(dsts[r] * B + b)) * H + unit] = h;
        }

        // --- publish: drain stores (to L2 / coherence point), then flag ---
        asm volatile("s_waitcnt vmcnt(0)" ::: "memory");
        if (l == 0) {
            if (fast) flagsw[role * 4] = (unsigned int)(t + 1);        // plain
            else      AT_ST(&flagsw[role * 4], (unsigned int)(t + 1)); // sc1
        }
    }
}

// ---------------------------------------------------------------------------
// Workspace: [0,1024) counters | nreg XCD regions + 1 fallback region |
// dest map. nreg sized to ws_size (round 5 proved >= ~4.5 MB available).
// ---------------------------------------------------------------------------
extern "C" void kernel_launch(void* const* d_in, const int* in_sizes, int n_in,
                              void* d_out, int out_size, void* d_ws, size_t ws_size,
                              hipStream_t stream) {
    const int*   tokens = (const int*)d_in[0];
    const float* emb    = (const float*)d_in[1];
    const float* w_ih   = (const float*)d_in[2];
    const float* w_hh   = (const float*)d_in[3];
    const float* b_ih   = (const float*)d_in[4];
    const float* b_hh   = (const float*)d_in[5];
    float* out = (float*)d_out;

    long long avail = (long long)ws_size - 1024 - 262144;
    int nreg = (int)(avail / REGION) - 1;   // reserve one region for fallback
    if (nreg > 8) nreg = 8;
    if (nreg < 0) nreg = 0;

    char* ws = (char*)d_ws;
    int* dest = (int*)(ws + 1024 + (size_t)(nreg + 1) * REGION);

    hipMemsetAsync(d_ws, 0, 1024 + (size_t)(nreg + 1) * REGION, stream);
    dest_kernel<<<B, 256, 0, stream>>>(tokens, dest);
    gru_kernel<<<1024, 64, 0, stream>>>(tokens, emb, w_ih, w_hh, b_ih, b_hh,
                                        dest, ws, nreg, out);
}

// Round 7
// 6807.003 us; speedup vs baseline: 1.4905x; 1.4905x over previous
//
#include <hip/hip_runtime.h>
#include <hip/hip_bf16.h>

typedef __attribute__((ext_vector_type(8))) short  bf16x8;
typedef __attribute__((ext_vector_type(4))) float  f32x4;

#define EOS 2
#define S 1024
#define B 64
#define E 256
#define H 512
#define NW 128            // 32 unit-groups x 4 batch-slices

// ws layout (704 KB total -- below round-3-proven 788 KB):
//   [0, 66048)            cnt: 4 slices x 1032 steps x 16B (uint + pad), zeroed
//   [131072, 655360)      hbuf: 2 bufs x {hi,lo} x [64][512] bf16, zeroed
//   [655360, 720896)      dest8 map [1024][64] int8 (written by dest_kernel)
#define CNT_SLOTS 1032
#define CNT_STRIDE 4      // uints per slot (16 B)
#define HBUF_OFF 131072
#define DEST_OFF 655360
#define MEMSET_BYTES 655360

#define AT_LD(p)    __hip_atomic_load((p), __ATOMIC_RELAXED, __HIP_MEMORY_SCOPE_AGENT)
#define AT_ST(p, v) __hip_atomic_store((p), (v), __ATOMIC_RELAXED, __HIP_MEMORY_SCOPE_AGENT)
#define AT_ADD(p,v) __hip_atomic_fetch_add((p), (v), __ATOMIC_RELAXED, __HIP_MEMORY_SCOPE_AGENT)

__device__ __forceinline__ unsigned short f2bf(float f) {
    unsigned int u = __builtin_bit_cast(unsigned int, f);
    unsigned int r = (u + 0x7FFFu + ((u >> 16) & 1u)) >> 16;
    return (unsigned short)r;
}
__device__ __forceinline__ float bf2f(unsigned short s) {
    unsigned int u = ((unsigned int)s) << 16;
    return __builtin_bit_cast(float, u);
}
__device__ __forceinline__ unsigned int pk2(float x, float y) {  // round-half-up pair
    unsigned int ux = __builtin_bit_cast(unsigned int, x) + 0x8000u;
    unsigned int uy = __builtin_bit_cast(unsigned int, y) + 0x8000u;
    return (ux >> 16) | (uy & 0xFFFF0000u);
}
__device__ __forceinline__ bf16x8 pack8hu(float4 a, float4 b) {
    union { unsigned int d[4]; bf16x8 v; } u;
    u.d[0] = pk2(a.x, a.y); u.d[1] = pk2(a.z, a.w);
    u.d[2] = pk2(b.x, b.y); u.d[3] = pk2(b.z, b.w);
    return u.v;
}
__device__ __forceinline__ bf16x8 pack8rne(float4 a, float4 b) {
    union { unsigned short s[8]; bf16x8 v; } u;
    u.s[0] = f2bf(a.x); u.s[1] = f2bf(a.y); u.s[2] = f2bf(a.z); u.s[3] = f2bf(a.w);
    u.s[4] = f2bf(b.x); u.s[5] = f2bf(b.y); u.s[6] = f2bf(b.z); u.s[7] = f2bf(b.w);
    return u.v;
}

// ---------------------------------------------------------------------------
// dest8[t][b] = k-th EOS index (0..31) or -1, int8
// ---------------------------------------------------------------------------
__global__ __launch_bounds__(256) void dest_kernel(const int* __restrict__ tokens,
                                                   signed char* __restrict__ dest8) {
    const int b = blockIdx.x, tid = threadIdx.x;
    const int l = tid & 63, w = tid >> 6;
    const int base = tid * 4;
    int m[4], cnt = 0;
#pragma unroll
    for (int i = 0; i < 4; ++i) {
        int tok = tokens[b * S + base + i];
        m[i] = (tok == EOS) ? 1 : 0;
        cnt += m[i];
    }
    int inc = cnt;
#pragma unroll
    for (int d = 1; d < 64; d <<= 1) {
        int v = __shfl_up(inc, d, 64);
        if (l >= d) inc += v;
    }
    __shared__ int wt[4];
    if (l == 63) wt[w] = inc;
    __syncthreads();
    int off = 0;
    for (int k = 0; k < 4; ++k)
        if (k < w) off += wt[k];
    int run = off + inc - cnt;  // exclusive prefix
#pragma unroll
    for (int i = 0; i < 4; ++i) {
        dest8[(base + i) * B + b] = m[i] ? (signed char)run : (signed char)-1;
        run += m[i];
    }
}

// ---------------------------------------------------------------------------
// Persistent fused GRU. 128 blocks x 64 thr (one wave each, ~1 block/CU).
// Wave wid: unit group j=wid>>2 (units [16j,16j+16)), batch slice w=wid&3
// (batches [16w,16w+16)). Weights register-resident bf16 (RNE). h exchanged
// via global bf16 hi/lo planes, double-buffered, agent-scope (sc1) atomics
// (round-3-verified). NEW vs round 3: sync via ONE counter per (slice,step)
// -- producer lane-0 atomicAdd, consumer polls a single uniform address
// (cuts poll fan-out 32x); publish before out-writes; all 64 h-loads batched.
// ---------------------------------------------------------------------------
__global__ __launch_bounds__(64, 1) void gru_kernel(
    const int* __restrict__ tokens, const float* __restrict__ emb,
    const float* __restrict__ w_ih, const float* __restrict__ w_hh,
    const float* __restrict__ b_ih, const float* __restrict__ b_hh,
    const signed char* __restrict__ dest8,
    char* ws, float* __restrict__ out) {

    const int wid = blockIdx.x;          // 0..127
    const int j = wid >> 2;              // unit group
    const int w = wid & 3;               // batch slice
    const int l = threadIdx.x;           // 0..63
    const int l15 = l & 15, quad = l >> 4;
    const int unit = j * 16 + l15;
    const int koff = quad * 8;
    const int brow = w * 16 + l15;

    unsigned int*   cnt  = (unsigned int*)ws;
    unsigned short* hbuf = (unsigned short*)(ws + HBUF_OFF);

    // ---- one-time: weight B-fragments into registers (RNE bf16) ----
    bf16x8 Wh[3][16];
#pragma unroll
    for (int g = 0; g < 3; ++g)
#pragma unroll
        for (int kt = 0; kt < 16; ++kt) {
            const float* p = &w_hh[(size_t)(g * H + unit) * H + kt * 32 + koff];
            Wh[g][kt] = pack8rne(*(const float4*)p, *(const float4*)(p + 4));
        }
    bf16x8 Wi[3][8];
#pragma unroll
    for (int g = 0; g < 3; ++g)
#pragma unroll
        for (int kt = 0; kt < 8; ++kt) {
            const float* p = &w_ih[(size_t)(g * H + unit) * E + kt * 32 + koff];
            Wi[g][kt] = pack8rne(*(const float4*)p, *(const float4*)(p + 4));
        }
    const float bi0 = b_ih[unit], bi1 = b_ih[H + unit], bi2 = b_ih[2 * H + unit];
    const float bh0 = b_hh[unit], bh1 = b_hh[H + unit], bh2 = b_hh[2 * H + unit];

    float hown[4] = {0.f, 0.f, 0.f, 0.f};
    int tok_next = tokens[brow * S];
    int budget = 1 << 22;                // anti-hang safety (total)

    for (int t = 0; t < S; ++t) {
        // --- independent work first (hides under producer wait) ---
        const int tok = tok_next;
        const float* er = &emb[(size_t)tok * E + koff];
        float4 ef[8][2];
#pragma unroll
        for (int kt = 0; kt < 8; ++kt) {
            ef[kt][0] = *(const float4*)(er + kt * 32);
            ef[kt][1] = *(const float4*)(er + kt * 32 + 4);
        }
        if (t + 1 < S) tok_next = tokens[brow * S + t + 1];
        unsigned int dword =
            *(const unsigned int*)&dest8[t * B + w * 16 + quad * 4];

        f32x4 gi0 = {bi0, bi0, bi0, bi0};
        f32x4 gi1 = {bi1, bi1, bi1, bi1};
        f32x4 gi2 = {bi2, bi2, bi2, bi2};
#pragma unroll
        for (int kt = 0; kt < 8; ++kt) {
            bf16x8 af = pack8hu(ef[kt][0], ef[kt][1]);
            gi0 = __builtin_amdgcn_mfma_f32_16x16x32_bf16(af, Wi[0][kt], gi0, 0, 0, 0);
            gi1 = __builtin_amdgcn_mfma_f32_16x16x32_bf16(af, Wi[1][kt], gi1, 0, 0, 0);
            gi2 = __builtin_amdgcn_mfma_f32_16x16x32_bf16(af, Wi[2][kt], gi2, 0, 0, 0);
        }

        // --- wait for h[t]: single aggregated counter, uniform address ---
        if (t > 0) {
            const unsigned int* cp = &cnt[((unsigned)w * CNT_SLOTS + (unsigned)t) * CNT_STRIDE];
            while (budget > 0) {
                unsigned int c = AT_LD(cp);
                if (c >= 32u) break;
                --budget;
            }
        }

        // --- gh = b_hh + h . W_hh^T (bf16 hi+lo split), 64 batched u64 loads ---
        const unsigned short* hs = hbuf + (size_t)(t & 1) * (2 * B * H);
        f32x4 a0 = {bh0, bh0, bh0, bh0};
        f32x4 a1 = {bh1, bh1, bh1, bh1};
        f32x4 a2 = {bh2, bh2, bh2, bh2};
        union U { unsigned long long q[2]; bf16x8 v; };
        U uh[16], ul[16];
#pragma unroll
        for (int kt = 0; kt < 16; ++kt) {
            const size_t off = (size_t)brow * H + kt * 32 + koff;
            const unsigned long long* qh = (const unsigned long long*)(hs + off);
            const unsigned long long* ql = (const unsigned long long*)(hs + B * H + off);
            uh[kt].q[0] = AT_LD(qh); uh[kt].q[1] = AT_LD(qh + 1);
            ul[kt].q[0] = AT_LD(ql); ul[kt].q[1] = AT_LD(ql + 1);
        }
#pragma unroll
        for (int kt = 0; kt < 16; ++kt) {
            a0 = __builtin_amdgcn_mfma_f32_16x16x32_bf16(uh[kt].v, Wh[0][kt], a0, 0, 0, 0);
            a1 = __builtin_amdgcn_mfma_f32_16x16x32_bf16(uh[kt].v, Wh[1][kt], a1, 0, 0, 0);
            a2 = __builtin_amdgcn_mfma_f32_16x16x32_bf16(uh[kt].v, Wh[2][kt], a2, 0, 0, 0);
            a0 = __builtin_amdgcn_mfma_f32_16x16x32_bf16(ul[kt].v, Wh[0][kt], a0, 0, 0, 0);
            a1 = __builtin_amdgcn_mfma_f32_16x16x32_bf16(ul[kt].v, Wh[1][kt], a1, 0, 0, 0);
            a2 = __builtin_amdgcn_mfma_f32_16x16x32_bf16(ul[kt].v, Wh[2][kt], a2, 0, 0, 0);
        }

        // --- gates + packed h[t+1] stores (hi|lo paired via shfl, sc1) ---
        unsigned short* hd = hbuf + (size_t)((t + 1) & 1) * (2 * B * H);
        unsigned int* hd_hi32 = (unsigned int*)hd;
        unsigned int* hd_lo32 = (unsigned int*)(hd + B * H);
        const bool even = (l15 & 1) == 0;
#pragma unroll
        for (int r = 0; r < 4; ++r) {
            const int b = w * 16 + quad * 4 + r;
            float rg = 1.f / (1.f + __expf(-(gi0[r] + a0[r])));
            float zg = 1.f / (1.f + __expf(-(gi1[r] + a1[r])));
            float x = gi2[r] + rg * a2[r];
            x = fminf(15.f, fmaxf(-15.f, x));
            float e = __expf(-2.f * x);
            float ng = (1.f - e) / (1.f + e);
            float h = (1.f - zg) * ng + zg * hown[r];   // fp32 carry (exact)
            hown[r] = h;
            unsigned short hi16 = f2bf(h);
            unsigned short lo16 = f2bf(h - bf2f(hi16));
            unsigned int pk = ((unsigned int)lo16 << 16) | (unsigned int)hi16;
            unsigned int sw = (unsigned int)__shfl_xor((int)pk, 1);
            unsigned int val = even ? ((pk & 0xFFFFu) | (sw << 16))
                                    : ((sw >> 16) | (pk & 0xFFFF0000u));
            unsigned int didx = ((unsigned int)(b * H + unit)) >> 1;
            AT_ST((even ? hd_hi32 : hd_lo32) + didx, val);
        }

        // --- publish FIRST: drain h stores, one atomicAdd per wave ---
        asm volatile("s_waitcnt vmcnt(0)" ::: "memory");
        if (l == 0)
            AT_ADD(&cnt[((unsigned)w * CNT_SLOTS + (unsigned)(t + 1)) * CNT_STRIDE], 1u);

        // --- out writes AFTER publish (off the critical chain) ---
#pragma unroll
        for (int r = 0; r < 4; ++r) {
            const int b = w * 16 + quad * 4 + r;
            int db = (int)(signed char)((dword >> (8 * r)) & 0xFFu);
            if (db >= 0)
                out[((size_t)(db * B + b)) * H + unit] = hown[r];
        }
    }
}

extern "C" void kernel_launch(void* const* d_in, const int* in_sizes, int n_in,
                              void* d_out, int out_size, void* d_ws, size_t ws_size,
                              hipStream_t stream) {
    const int*   tokens = (const int*)d_in[0];
    const float* emb    = (const float*)d_in[1];
    const float* w_ih   = (const float*)d_in[2];
    const float* w_hh   = (const float*)d_in[3];
    const float* b_ih   = (const float*)d_in[4];
    const float* b_hh   = (const float*)d_in[5];
    float* out = (float*)d_out;

    char* ws = (char*)d_ws;
    signed char* dest8 = (signed char*)(ws + DEST_OFF);

    hipMemsetAsync(d_ws, 0, MEMSET_BYTES, stream);   // counters + h0 = 0
    dest_kernel<<<B, 256, 0, stream>>>(tokens, dest8);
    gru_kernel<<<NW, 64, 0, stream>>>(tokens, emb, w_ih, w_hh, b_ih, b_hh,
                                      dest8, ws, out);
}

// Round 8
// 5558.285 us; speedup vs baseline: 1.8253x; 1.2247x over previous
//
#include <hip/hip_runtime.h>
#include <hip/hip_bf16.h>

typedef __attribute__((ext_vector_type(8))) short  bf16x8;
typedef __attribute__((ext_vector_type(4))) float  f32x4;
typedef __attribute__((ext_vector_type(4))) unsigned int u32x4;

#define EOS 2
#define S 1024
#define B 64
#define E 256
#define H 512

// ws layout (704 KB total -- below round-3-proven 788 KB):
//   [0, 66048)            cnt: 4 slices x 1032 steps x 16B (uint+pad), zeroed
//   [131072, 655360)      hbuf: 2 bufs x {hi,lo} x [64][512] bf16, zeroed
//   [655360, 720896)      dest8 map [1024][64] int8 (written by dest_kernel)
#define CNT_SLOTS 1032
#define CNT_STRIDE 4
#define HBUF_OFF 131072
#define DEST_OFF 655360
#define MEMSET_BYTES 655360

#define AT_LD(p)    __hip_atomic_load((p), __ATOMIC_RELAXED, __HIP_MEMORY_SCOPE_AGENT)
#define AT_ST(p, v) __hip_atomic_store((p), (v), __ATOMIC_RELAXED, __HIP_MEMORY_SCOPE_AGENT)
#define AT_ADD(p,v) __hip_atomic_fetch_add((p), (v), __ATOMIC_RELAXED, __HIP_MEMORY_SCOPE_AGENT)

__device__ __forceinline__ unsigned short f2bf(float f) {
    unsigned int u = __builtin_bit_cast(unsigned int, f);
    unsigned int r = (u + 0x7FFFu + ((u >> 16) & 1u)) >> 16;
    return (unsigned short)r;
}
__device__ __forceinline__ float bf2f(unsigned short s) {
    unsigned int u = ((unsigned int)s) << 16;
    return __builtin_bit_cast(float, u);
}
__device__ __forceinline__ unsigned int pk2(float x, float y) {  // round-half-up pair
    unsigned int ux = __builtin_bit_cast(unsigned int, x) + 0x8000u;
    unsigned int uy = __builtin_bit_cast(unsigned int, y) + 0x8000u;
    return (ux >> 16) | (uy & 0xFFFF0000u);
}
__device__ __forceinline__ bf16x8 pack8hu(float4 a, float4 b) {
    union { unsigned int d[4]; bf16x8 v; } u;
    u.d[0] = pk2(a.x, a.y); u.d[1] = pk2(a.z, a.w);
    u.d[2] = pk2(b.x, b.y); u.d[3] = pk2(b.z, b.w);
    return u.v;
}
__device__ __forceinline__ bf16x8 pack8rne(float4 a, float4 b) {
    union { unsigned short s[8]; bf16x8 v; } u;
    u.s[0] = f2bf(a.x); u.s[1] = f2bf(a.y); u.s[2] = f2bf(a.z); u.s[3] = f2bf(a.w);
    u.s[4] = f2bf(b.x); u.s[5] = f2bf(b.y); u.s[6] = f2bf(b.z); u.s[7] = f2bf(b.w);
    return u.v;
}

// ---------------------------------------------------------------------------
// dest8[t][b] = k-th EOS index (0..31) or -1, int8
// ---------------------------------------------------------------------------
__global__ __launch_bounds__(256) void dest_kernel(const int* __restrict__ tokens,
                                                   signed char* __restrict__ dest8) {
    const int b = blockIdx.x, tid = threadIdx.x;
    const int l = tid & 63, w = tid >> 6;
    const int base = tid * 4;
    int m[4], cnt = 0;
#pragma unroll
    for (int i = 0; i < 4; ++i) {
        int tok = tokens[b * S + base + i];
        m[i] = (tok == EOS) ? 1 : 0;
        cnt += m[i];
    }
    int inc = cnt;
#pragma unroll
    for (int d = 1; d < 64; d <<= 1) {
        int v = __shfl_up(inc, d, 64);
        if (l >= d) inc += v;
    }
    __shared__ int wt[4];
    if (l == 63) wt[w] = inc;
    __syncthreads();
    int off = 0;
    for (int k = 0; k < 4; ++k)
        if (k < w) off += wt[k];
    int run = off + inc - cnt;  // exclusive prefix
#pragma unroll
    for (int i = 0; i < 4; ++i) {
        dest8[(base + i) * B + b] = m[i] ? (signed char)run : (signed char)-1;
        run += m[i];
    }
}

// ---------------------------------------------------------------------------
// Persistent fused GRU, WG-cooperative. 32 WGs x 256 thr (4 waves, 1/SIMD ->
// full register budget, weights stay register/AGPR-resident). WG (j4,w):
// unit-groups 4*j4..4*j4+3 of batch slice w. The 4 waves SHARE one LDS h
// stage: 256 threads load the slice's h (hi+lo, 32 KB) from global ONCE per
// WG -> 4x less agent-scope (L3) load volume than round 7's per-wave loads.
// Sync: one counter per (slice,step); producer = 1 atomicAdd per WG (8 per
// slice); consumer polls one uniform dword until >=8. Protocol & math are
// the round-3/7-verified sc1 path (bf16 hi/lo transport, fp32 carry).
// ---------------------------------------------------------------------------
__global__ __launch_bounds__(256, 1) void gru_kernel(
    const int* __restrict__ tokens, const float* __restrict__ emb,
    const float* __restrict__ w_ih, const float* __restrict__ w_hh,
    const float* __restrict__ b_ih, const float* __restrict__ b_hh,
    const signed char* __restrict__ dest8,
    char* ws, float* __restrict__ out) {

    const int tid = threadIdx.x;         // 0..255
    const int wv = tid >> 6;             // wave in WG (0..3)
    const int l = tid & 63;
    const int l15 = l & 15, quad = l >> 4;
    const int blk = blockIdx.x;          // 0..31
    const int w = blk & 3;               // batch slice
    const int j4 = blk >> 2;             // unit-group quad (0..7)
    const int unit = (j4 * 4 + wv) * 16 + l15;
    const int koff = quad * 8;
    const int brow = w * 16 + l15;

    unsigned int*   cnt  = (unsigned int*)ws;
    unsigned short* hbuf = (unsigned short*)(ws + HBUF_OFF);

    __shared__ alignas(16) unsigned short sh[2][16][520];  // {hi,lo} x rows x units(+8 pad)

    // ---- one-time: weight B-fragments into registers (RNE bf16) ----
    bf16x8 Wh[3][16];
#pragma unroll
    for (int g = 0; g < 3; ++g)
#pragma unroll
        for (int kt = 0; kt < 16; ++kt) {
            const float* p = &w_hh[(size_t)(g * H + unit) * H + kt * 32 + koff];
            Wh[g][kt] = pack8rne(*(const float4*)p, *(const float4*)(p + 4));
        }
    bf16x8 Wi[3][8];
#pragma unroll
    for (int g = 0; g < 3; ++g)
#pragma unroll
        for (int kt = 0; kt < 8; ++kt) {
            const float* p = &w_ih[(size_t)(g * H + unit) * E + kt * 32 + koff];
            Wi[g][kt] = pack8rne(*(const float4*)p, *(const float4*)(p + 4));
        }
    const float bi0 = b_ih[unit], bi1 = b_ih[H + unit], bi2 = b_ih[2 * H + unit];
    const float bh0 = b_hh[unit], bh1 = b_hh[H + unit], bh2 = b_hh[2 * H + unit];

    float hown[4] = {0.f, 0.f, 0.f, 0.f};
    int tok_next = tokens[brow * S];
    int budget = 1 << 22;

    // staging map: thread -> (plane p, row rr, 16B column chunk t7), 8 chunks
    // strided 128B so each instruction is 128B-coalesced across 8 lanes.
    const int p_st  = tid >> 7;          // 0..1 (hi/lo plane)
    const int rr_st = (tid >> 3) & 15;   // row 0..15
    const int t7    = tid & 7;           // 16B sub-column

    for (int t = 0; t < S; ++t) {
        // --- independent work first (hides under producer wait) ---
        const int tok = tok_next;
        const float* er = &emb[(size_t)tok * E + koff];
        float4 ef[8][2];
#pragma unroll
        for (int kt = 0; kt < 8; ++kt) {
            ef[kt][0] = *(const float4*)(er + kt * 32);
            ef[kt][1] = *(const float4*)(er + kt * 32 + 4);
        }
        if (t + 1 < S) tok_next = tokens[brow * S + t + 1];
        unsigned int dword =
            *(const unsigned int*)&dest8[t * B + w * 16 + quad * 4];

        f32x4 gi0 = {bi0, bi0, bi0, bi0};
        f32x4 gi1 = {bi1, bi1, bi1, bi1};
        f32x4 gi2 = {bi2, bi2, bi2, bi2};
#pragma unroll
        for (int kt = 0; kt < 8; ++kt) {
            bf16x8 af = pack8hu(ef[kt][0], ef[kt][1]);
            gi0 = __builtin_amdgcn_mfma_f32_16x16x32_bf16(af, Wi[0][kt], gi0, 0, 0, 0);
            gi1 = __builtin_amdgcn_mfma_f32_16x16x32_bf16(af, Wi[1][kt], gi1, 0, 0, 0);
            gi2 = __builtin_amdgcn_mfma_f32_16x16x32_bf16(af, Wi[2][kt], gi2, 0, 0, 0);
        }

        // --- wait for h[t]: the 8 producer WGs of slice w ---
        if (t > 0) {
            const unsigned int* cp =
                &cnt[((unsigned)w * CNT_SLOTS + (unsigned)t) * CNT_STRIDE];
            while (budget > 0) {
                unsigned int c = AT_LD(cp);
                if (c >= 8u) break;
                --budget;
            }
        }

        // --- cooperative stage: 32 KB (hi+lo of slice rows) global -> LDS ---
        {
            const unsigned short* hs = hbuf + (size_t)(t & 1) * (2 * B * H);
            const unsigned short* gp =
                hs + (size_t)p_st * (B * H) + (size_t)(w * 16 + rr_st) * H + t7 * 8;
            u32x4 gr[8];
            asm volatile(
                "global_load_dwordx4 %0, %8, off sc1\n\t"
                "global_load_dwordx4 %1, %8, off offset:128 sc1\n\t"
                "global_load_dwordx4 %2, %8, off offset:256 sc1\n\t"
                "global_load_dwordx4 %3, %8, off offset:384 sc1\n\t"
                "global_load_dwordx4 %4, %8, off offset:512 sc1\n\t"
                "global_load_dwordx4 %5, %8, off offset:640 sc1\n\t"
                "global_load_dwordx4 %6, %8, off offset:768 sc1\n\t"
                "global_load_dwordx4 %7, %8, off offset:896 sc1\n\t"
                "s_waitcnt vmcnt(0)"
                : "=&v"(gr[0]), "=&v"(gr[1]), "=&v"(gr[2]), "=&v"(gr[3]),
                  "=&v"(gr[4]), "=&v"(gr[5]), "=&v"(gr[6]), "=&v"(gr[7])
                : "v"(gp)
                : "memory");
#pragma unroll
            for (int c = 0; c < 8; ++c)
                *(u32x4*)&sh[p_st][rr_st][t7 * 8 + c * 64] = gr[c];
        }
        __syncthreads();   // stage complete -> frags readable

        // --- gh = b_hh + h . W_hh^T (bf16 hi+lo split) from LDS ---
        f32x4 a0 = {bh0, bh0, bh0, bh0};
        f32x4 a1 = {bh1, bh1, bh1, bh1};
        f32x4 a2 = {bh2, bh2, bh2, bh2};
#pragma unroll
        for (int kt = 0; kt < 16; ++kt) {
            bf16x8 ah = *(const bf16x8*)&sh[0][l15][kt * 32 + koff];
            bf16x8 al = *(const bf16x8*)&sh[1][l15][kt * 32 + koff];
            a0 = __builtin_amdgcn_mfma_f32_16x16x32_bf16(ah, Wh[0][kt], a0, 0, 0, 0);
            a1 = __builtin_amdgcn_mfma_f32_16x16x32_bf16(ah, Wh[1][kt], a1, 0, 0, 0);
            a2 = __builtin_amdgcn_mfma_f32_16x16x32_bf16(ah, Wh[2][kt], a2, 0, 0, 0);
            a0 = __builtin_amdgcn_mfma_f32_16x16x32_bf16(al, Wh[0][kt], a0, 0, 0, 0);
            a1 = __builtin_amdgcn_mfma_f32_16x16x32_bf16(al, Wh[1][kt], a1, 0, 0, 0);
            a2 = __builtin_amdgcn_mfma_f32_16x16x32_bf16(al, Wh[2][kt], a2, 0, 0, 0);
        }

        // --- gates + packed h[t+1] stores (hi|lo paired via shfl, sc1) ---
        unsigned short* hd = hbuf + (size_t)((t + 1) & 1) * (2 * B * H);
        unsigned int* hd_hi32 = (unsigned int*)hd;
        unsigned int* hd_lo32 = (unsigned int*)(hd + B * H);
        const bool even = (l15 & 1) == 0;
#pragma unroll
        for (int r = 0; r < 4; ++r) {
            const int b = w * 16 + quad * 4 + r;
            float rg = 1.f / (1.f + __expf(-(gi0[r] + a0[r])));
            float zg = 1.f / (1.f + __expf(-(gi1[r] + a1[r])));
            float x = gi2[r] + rg * a2[r];
            x = fminf(15.f, fmaxf(-15.f, x));
            float e = __expf(-2.f * x);
            float ng = (1.f - e) / (1.f + e);
            float h = (1.f - zg) * ng + zg * hown[r];   // fp32 carry (exact)
            hown[r] = h;
            unsigned short hi16 = f2bf(h);
            unsigned short lo16 = f2bf(h - bf2f(hi16));
            unsigned int pk = ((unsigned int)lo16 << 16) | (unsigned int)hi16;
            unsigned int sw = (unsigned int)__shfl_xor((int)pk, 1);
            unsigned int val = even ? ((pk & 0xFFFFu) | (sw << 16))
                                    : ((sw >> 16) | (pk & 0xFFFF0000u));
            unsigned int didx = ((unsigned int)(b * H + unit)) >> 1;
            AT_ST((even ? hd_hi32 : hd_lo32) + didx, val);
        }

        // --- publish: per-wave drain, WG barrier, one atomicAdd per WG ---
        asm volatile("s_waitcnt vmcnt(0)" ::: "memory");
        __syncthreads();   // all 4 waves' h-stores drained; also fences LDS reuse
        if (tid == 0)
            AT_ADD(&cnt[((unsigned)w * CNT_SLOTS + (unsigned)(t + 1)) * CNT_STRIDE], 1u);

        // --- out writes AFTER publish (off the critical chain) ---
#pragma unroll
        for (int r = 0; r < 4; ++r) {
            const int b = w * 16 + quad * 4 + r;
            int db = (int)(signed char)((dword >> (8 * r)) & 0xFFu);
            if (db >= 0)
                out[((size_t)(db * B + b)) * H + unit] = hown[r];
        }
    }
}

extern "C" void kernel_launch(void* const* d_in, const int* in_sizes, int n_in,
                              void* d_out, int out_size, void* d_ws, size_t ws_size,
                              hipStream_t stream) {
    const int*   tokens = (const int*)d_in[0];
    const float* emb    = (const float*)d_in[1];
    const float* w_ih   = (const float*)d_in[2];
    const float* w_hh   = (const float*)d_in[3];
    const float* b_ih   = (const float*)d_in[4];
    const float* b_hh   = (const float*)d_in[5];
    float* out = (float*)d_out;

    char* ws = (char*)d_ws;
    signed char* dest8 = (signed char*)(ws + DEST_OFF);

    hipMemsetAsync(d_ws, 0, MEMSET_BYTES, stream);   // counters + h0 = 0
    dest_kernel<<<B, 256, 0, stream>>>(tokens, dest8);
    gru_kernel<<<32, 256, 0, stream>>>(tokens, emb, w_ih, w_hh, b_ih, b_hh,
                                       dest8, ws, out);
}

// Round 9
// 5384.673 us; speedup vs baseline: 1.8841x; 1.0322x over previous
//
#include <hip/hip_runtime.h>
#include <hip/hip_bf16.h>

typedef __attribute__((ext_vector_type(8))) short  bf16x8;
typedef __attribute__((ext_vector_type(4))) float  f32x4;
typedef __attribute__((ext_vector_type(4))) unsigned int u32x4;

#define EOS 2
#define S 1024
#define B 64
#define E 256
#define H 512
#define SENT 0xFFFFFFFFu

// ws layout (594 KB total -- below round-7/8-proven 720 KB):
//   [4096, 4096+512K)     hbuf: 4 slots x {hi,lo} x [64][512] bf16
//                         slot0 = 0 (h0), slots1-3 = 0xFF (sentinel)
//   [528384, 593920)      dest8 map [1024][64] int8
#define HBUF_OFF 4096
#define SLOT (2 * B * H)              // shorts per slot (hi+lo)
#define DEST_OFF (HBUF_OFF + 4 * SLOT * 2)

#define AT_ST(p, v) __hip_atomic_store((p), (v), __ATOMIC_RELAXED, __HIP_MEMORY_SCOPE_AGENT)

__device__ __forceinline__ unsigned short f2bf(float f) {
    unsigned int u = __builtin_bit_cast(unsigned int, f);
    unsigned int r = (u + 0x7FFFu + ((u >> 16) & 1u)) >> 16;
    return (unsigned short)r;
}
__device__ __forceinline__ float bf2f(unsigned short s) {
    unsigned int u = ((unsigned int)s) << 16;
    return __builtin_bit_cast(float, u);
}
__device__ __forceinline__ unsigned int pk2(float x, float y) {  // round-half-up pair
    unsigned int ux = __builtin_bit_cast(unsigned int, x) + 0x8000u;
    unsigned int uy = __builtin_bit_cast(unsigned int, y) + 0x8000u;
    return (ux >> 16) | (uy & 0xFFFF0000u);
}
__device__ __forceinline__ bf16x8 pack8hu(float4 a, float4 b) {
    union { unsigned int d[4]; bf16x8 v; } u;
    u.d[0] = pk2(a.x, a.y); u.d[1] = pk2(a.z, a.w);
    u.d[2] = pk2(b.x, b.y); u.d[3] = pk2(b.z, b.w);
    return u.v;
}
__device__ __forceinline__ bf16x8 pack8rne(float4 a, float4 b) {
    union { unsigned short s[8]; bf16x8 v; } u;
    u.s[0] = f2bf(a.x); u.s[1] = f2bf(a.y); u.s[2] = f2bf(a.z); u.s[3] = f2bf(a.w);
    u.s[4] = f2bf(b.x); u.s[5] = f2bf(b.y); u.s[6] = f2bf(b.z); u.s[7] = f2bf(b.w);
    return u.v;
}

// ---------------------------------------------------------------------------
// dest8[t][b] = k-th EOS index (0..31) or -1, int8
// ---------------------------------------------------------------------------
__global__ __launch_bounds__(256) void dest_kernel(const int* __restrict__ tokens,
                                                   signed char* __restrict__ dest8) {
    const int b = blockIdx.x, tid = threadIdx.x;
    const int l = tid & 63, w = tid >> 6;
    const int base = tid * 4;
    int m[4], cnt = 0;
#pragma unroll
    for (int i = 0; i < 4; ++i) {
        int tok = tokens[b * S + base + i];
        m[i] = (tok == EOS) ? 1 : 0;
        cnt += m[i];
    }
    int inc = cnt;
#pragma unroll
    for (int d = 1; d < 64; d <<= 1) {
        int v = __shfl_up(inc, d, 64);
        if (l >= d) inc += v;
    }
    __shared__ int wt[4];
    if (l == 63) wt[w] = inc;
    __syncthreads();
    int off = 0;
    for (int k = 0; k < 4; ++k)
        if (k < w) off += wt[k];
    int run = off + inc - cnt;  // exclusive prefix
#pragma unroll
    for (int i = 0; i < 4; ++i) {
        dest8[(base + i) * B + b] = m[i] ? (signed char)run : (signed char)-1;
        run += m[i];
    }
}

// ---------------------------------------------------------------------------
// Persistent fused GRU, sentinel-sync edition. 32 WGs x 256 thr.
// WG (j4,w): unit-groups 4*j4..4*j4+3 of batch slice w; writes h block
// rows [16w,16w+16) x units [64*j4,64*j4+64). h rotates through 4 slots;
// unwritten dwords hold SENT (bf16-NaN pair, unreachable by finite h).
// Consumers poll the DATA (32KB cooperative sc1 loads) until sentinel-free:
// ready-detect and delivery share one L3 round trip -- no flags/counters/
// forward drains (round 8's 4-RTT chain -> 2). Reuse safety: during step t
// each WG re-sentinels its own region of slot (t+2)%4, drained by a vmcnt(0)
// hidden under compute, before its h[t+1] stores (skew<=1 proof in session
// notes). LDS stage is XOR-swizzled (chunk^(row&7), stride 512): staging
// writes and A-frag ds_read_b128 are 2-way (free) vs round 8's 8-way.
// ---------------------------------------------------------------------------
__global__ __launch_bounds__(256, 1) void gru_kernel(
    const int* __restrict__ tokens, const float* __restrict__ emb,
    const float* __restrict__ w_ih, const float* __restrict__ w_hh,
    const float* __restrict__ b_ih, const float* __restrict__ b_hh,
    const signed char* __restrict__ dest8,
    char* ws, float* __restrict__ out) {

    const int tid = threadIdx.x;         // 0..255
    const int wv = tid >> 6;             // wave in WG (0..3)
    const int l = tid & 63;
    const int l15 = l & 15, quad = l >> 4;
    const int blk = blockIdx.x;          // 0..31
    const int w = blk & 3;               // batch slice
    const int j4 = blk >> 2;             // unit-group quad (0..7)
    const int unit = (j4 * 4 + wv) * 16 + l15;
    const int koff = quad * 8;
    const int brow = w * 16 + l15;

    unsigned short* hbuf = (unsigned short*)(ws + HBUF_OFF);

    __shared__ alignas(16) unsigned short sh[2][16][512];  // {hi,lo} x rows x units, XOR-swizzled

    // ---- one-time: weight B-fragments into registers (RNE bf16) ----
    bf16x8 Wh[3][16];
#pragma unroll
    for (int g = 0; g < 3; ++g)
#pragma unroll
        for (int kt = 0; kt < 16; ++kt) {
            const float* p = &w_hh[(size_t)(g * H + unit) * H + kt * 32 + koff];
            Wh[g][kt] = pack8rne(*(const float4*)p, *(const float4*)(p + 4));
        }
    bf16x8 Wi[3][8];
#pragma unroll
    for (int g = 0; g < 3; ++g)
#pragma unroll
        for (int kt = 0; kt < 8; ++kt) {
            const float* p = &w_ih[(size_t)(g * H + unit) * E + kt * 32 + koff];
            Wi[g][kt] = pack8rne(*(const float4*)p, *(const float4*)(p + 4));
        }
    const float bi0 = b_ih[unit], bi1 = b_ih[H + unit], bi2 = b_ih[2 * H + unit];
    const float bh0 = b_hh[unit], bh1 = b_hh[H + unit], bh2 = b_hh[2 * H + unit];

    float hown[4] = {0.f, 0.f, 0.f, 0.f};
    int tok_next = tokens[brow * S];
    int budget = 1 << 21;                // anti-hang safety (total poll iters)

    // staging map: thread -> (plane, row, 16B chunk column), chunks strided
    // 128B so each load instruction is 128B-coalesced across 8 lanes.
    const int p_st  = tid >> 7;          // 0..1 (hi/lo plane)
    const int rr_st = (tid >> 3) & 15;   // row 0..15
    const int t7    = tid & 7;           // 16B sub-column

    for (int t = 0; t < S; ++t) {
        // --- independent work first (overlaps the data poll) ---
        const int tok = tok_next;
        const float* er = &emb[(size_t)tok * E + koff];
        float4 ef[8][2];
#pragma unroll
        for (int kt = 0; kt < 8; ++kt) {
            ef[kt][0] = *(const float4*)(er + kt * 32);
            ef[kt][1] = *(const float4*)(er + kt * 32 + 4);
        }
        if (t + 1 < S) tok_next = tokens[brow * S + t + 1];
        unsigned int dword =
            *(const unsigned int*)&dest8[t * B + w * 16 + quad * 4];

        f32x4 gi0 = {bi0, bi0, bi0, bi0};
        f32x4 gi1 = {bi1, bi1, bi1, bi1};
        f32x4 gi2 = {bi2, bi2, bi2, bi2};
#pragma unroll
        for (int kt = 0; kt < 8; ++kt) {
            bf16x8 af = pack8hu(ef[kt][0], ef[kt][1]);
            gi0 = __builtin_amdgcn_mfma_f32_16x16x32_bf16(af, Wi[0][kt], gi0, 0, 0, 0);
            gi1 = __builtin_amdgcn_mfma_f32_16x16x32_bf16(af, Wi[1][kt], gi1, 0, 0, 0);
            gi2 = __builtin_amdgcn_mfma_f32_16x16x32_bf16(af, Wi[2][kt], gi2, 0, 0, 0);
        }

        // --- cooperative stage WITH sentinel poll: data IS the ready flag ---
        {
            const unsigned short* hs = hbuf + (size_t)(t & 3) * SLOT;
            const unsigned short* gp =
                hs + (size_t)p_st * (B * H) + (size_t)(w * 16 + rr_st) * H + t7 * 8;
            u32x4 gr[8];
            unsigned int bad;
            do {
                asm volatile(
                    "global_load_dwordx4 %0, %8, off sc1\n\t"
                    "global_load_dwordx4 %1, %8, off offset:128 sc1\n\t"
                    "global_load_dwordx4 %2, %8, off offset:256 sc1\n\t"
                    "global_load_dwordx4 %3, %8, off offset:384 sc1\n\t"
                    "global_load_dwordx4 %4, %8, off offset:512 sc1\n\t"
                    "global_load_dwordx4 %5, %8, off offset:640 sc1\n\t"
                    "global_load_dwordx4 %6, %8, off offset:768 sc1\n\t"
                    "global_load_dwordx4 %7, %8, off offset:896 sc1\n\t"
                    "s_waitcnt vmcnt(0)"
                    : "=&v"(gr[0]), "=&v"(gr[1]), "=&v"(gr[2]), "=&v"(gr[3]),
                      "=&v"(gr[4]), "=&v"(gr[5]), "=&v"(gr[6]), "=&v"(gr[7])
                    : "v"(gp)
                    : "memory");
                bad = 0;
#pragma unroll
                for (int c = 0; c < 8; ++c)
                    bad |= (unsigned)((gr[c][0] == SENT) | (gr[c][1] == SENT) |
                                      (gr[c][2] == SENT) | (gr[c][3] == SENT));
            } while (bad && --budget > 0);
            // XOR-swizzled LDS placement: chunk index c8 = t7 + 8*c
#pragma unroll
            for (int c = 0; c < 8; ++c) {
                int pos = ((t7 + 8 * c) ^ (rr_st & 7)) * 8;
                *(u32x4*)&sh[p_st][rr_st][pos] = gr[c];
            }
        }

        // --- re-sentinel own write region of slot (t+2)%4 (drain is later,
        //     hidden under the MFMA chain) ---
        {
            unsigned short* rs = hbuf + (size_t)((t + 2) & 3) * SLOT;
            const size_t rbase = (size_t)(w * 16 + (tid >> 4)) * H + j4 * 64;
            unsigned int* ph = (unsigned int*)(rs + rbase) + (tid & 15) * 2;
            unsigned int* pl = (unsigned int*)(rs + B * H + rbase) + (tid & 15) * 2;
            AT_ST(ph, SENT); AT_ST(ph + 1, SENT);
            AT_ST(pl, SENT); AT_ST(pl + 1, SENT);
        }
        __syncthreads();   // stage complete -> frags readable

        // --- gh = b_hh + h . W_hh^T (bf16 hi+lo split) from swizzled LDS ---
        f32x4 a0 = {bh0, bh0, bh0, bh0};
        f32x4 a1 = {bh1, bh1, bh1, bh1};
        f32x4 a2 = {bh2, bh2, bh2, bh2};
#pragma unroll
        for (int kt = 0; kt < 16; ++kt) {
            const int pos = ((kt * 4 + quad) ^ (l15 & 7)) * 8;
            bf16x8 ah = *(const bf16x8*)&sh[0][l15][pos];
            bf16x8 al = *(const bf16x8*)&sh[1][l15][pos];
            a0 = __builtin_amdgcn_mfma_f32_16x16x32_bf16(ah, Wh[0][kt], a0, 0, 0, 0);
            a1 = __builtin_amdgcn_mfma_f32_16x16x32_bf16(ah, Wh[1][kt], a1, 0, 0, 0);
            a2 = __builtin_amdgcn_mfma_f32_16x16x32_bf16(ah, Wh[2][kt], a2, 0, 0, 0);
            a0 = __builtin_amdgcn_mfma_f32_16x16x32_bf16(al, Wh[0][kt], a0, 0, 0, 0);
            a1 = __builtin_amdgcn_mfma_f32_16x16x32_bf16(al, Wh[1][kt], a1, 0, 0, 0);
            a2 = __builtin_amdgcn_mfma_f32_16x16x32_bf16(al, Wh[2][kt], a2, 0, 0, 0);
        }

        // --- gates ---
        float hval[4];
        unsigned int pkv[4];
#pragma unroll
        for (int r = 0; r < 4; ++r) {
            float rg = 1.f / (1.f + __expf(-(gi0[r] + a0[r])));
            float zg = 1.f / (1.f + __expf(-(gi1[r] + a1[r])));
            float x = gi2[r] + rg * a2[r];
            x = fminf(15.f, fmaxf(-15.f, x));
            float e = __expf(-2.f * x);
            float ng = (1.f - e) / (1.f + e);
            float h = (1.f - zg) * ng + zg * hown[r];   // fp32 carry (exact)
            hown[r] = h; hval[r] = h;
            unsigned short hi16 = f2bf(h);
            unsigned short lo16 = f2bf(h - bf2f(hi16));
            pkv[r] = ((unsigned int)lo16 << 16) | (unsigned int)hi16;
        }

        // --- drain (resets + stage loads; mostly already landed), then
        //     publish h[t+1]: the stores themselves are the ready signal ---
        asm volatile("s_waitcnt vmcnt(0)" ::: "memory");
        {
            unsigned short* hd = hbuf + (size_t)((t + 1) & 3) * SLOT;
            unsigned int* hd_hi32 = (unsigned int*)hd;
            unsigned int* hd_lo32 = (unsigned int*)(hd + B * H);
            const bool even = (l15 & 1) == 0;
#pragma unroll
            for (int r = 0; r < 4; ++r) {
                const int b = w * 16 + quad * 4 + r;
                unsigned int sw = (unsigned int)__shfl_xor((int)pkv[r], 1);
                unsigned int val = even ? ((pkv[r] & 0xFFFFu) | (sw << 16))
                                        : ((sw >> 16) | (pkv[r] & 0xFFFF0000u));
                unsigned int didx = ((unsigned int)(b * H + unit)) >> 1;
                AT_ST((even ? hd_hi32 : hd_lo32) + didx, val);
            }
        }
        __syncthreads();   // all waves done reading sh -> next stage may write

        // --- out writes AFTER publish (off the critical chain) ---
#pragma unroll
        for (int r = 0; r < 4; ++r) {
            const int b = w * 16 + quad * 4 + r;
            int db = (int)(signed char)((dword >> (8 * r)) & 0xFFu);
            if (db >= 0)
                out[((size_t)(db * B + b)) * H + unit] = hval[r];
        }
    }
}

extern "C" void kernel_launch(void* const* d_in, const int* in_sizes, int n_in,
                              void* d_out, int out_size, void* d_ws, size_t ws_size,
                              hipStream_t stream) {
    const int*   tokens = (const int*)d_in[0];
    const float* emb    = (const float*)d_in[1];
    const float* w_ih   = (const float*)d_in[2];
    const float* w_hh   = (const float*)d_in[3];
    const float* b_ih   = (const float*)d_in[4];
    const float* b_hh   = (const float*)d_in[5];
    float* out = (float*)d_out;

    char* ws = (char*)d_ws;
    signed char* dest8 = (signed char*)(ws + DEST_OFF);

    // slot0 = zeros (h0, immediately valid); slots 1-3 = sentinel 0xFF bytes
    hipMemsetAsync(ws + HBUF_OFF, 0, SLOT * 2, stream);
    hipMemsetAsync(ws + HBUF_OFF + SLOT * 2, 0xFF, 3 * SLOT * 2, stream);
    dest_kernel<<<B, 256, 0, stream>>>(tokens, dest8);
    gru_kernel<<<32, 256, 0, stream>>>(tokens, emb, w_ih, w_hh, b_ih, b_hh,
                                       dest8, ws, out);
}